// Round 1
// 333.398 us; speedup vs baseline: 1.0393x; 1.0393x over previous
//
#include <hip/hip_runtime.h>

// SSIM loss, streaming-row kernel, no LDS in the hot loop, no barriers.
// r5: counters showed latency-bound (VALUBusy 43%, HBM 7.6%, Occupancy 21%
// = 2 waves/SIMD). Cause: 5 maps x 2 cols x 11 rolling accumulators = 110
// always-live regs -> ~195-reg working set -> 2 blocks/CU. Fix: 1 output
// col per thread (55 accumulators), __launch_bounds__(256,4) caps at 128
// VGPR -> 4 blocks/CU. Grid 16 x 2 x 96 = 3072 blocks = 3 packed rounds.
// Odd-column alignment handled with a per-lane hoisted 12-tap weight
// vector W (parity-shifted Gaussian + zero pad tap): loads stay 8B-aligned
// float2, all array indices stay literal (SROA guaranteed), no divergence,
// and fmaf(0,x,h)==h keeps the blur bit-exact vs the 11-tap order.

#define IMG 512
#define OUT_DIM 502    // 512 - 10 (VALID conv twice)
#define WIN 11
#define BH 32          // output rows per band
#define NPHASE (BH + WIN - 1)   // 42
#define NPLANES 96

template<int PH>
__device__ __forceinline__ void phase_step(int base, int r0, int c, int cbase,
                                           const float* __restrict__ Xp,
                                           const float* __restrict__ Yp,
                                           const float (&W)[12],
                                           float (&a)[5][WIN], float& local) {
    // Gaussian(11, sigma=1.5), normalized; matches numpy fp32 (absmax 0.0).
    constexpr float G[WIN] = {0.00102838f, 0.00759875f, 0.03600077f, 0.10936071f,
                              0.21300553f, 0.26601172f, 0.21300553f, 0.10936071f,
                              0.03600077f, 0.00759875f, 0.00102838f};
    const int p = base + PH;
    if (p >= NPHASE) return;                  // uniform; only last outer iter
    const int rr = min(r0 + p, IMG - 1);      // clamped rows feed only discarded outputs
    const float* px = Xp + rr * IMG + cbase;
    const float* py = Yp + rr * IMG + cbase;

    float x[12], y[12];
    #pragma unroll
    for (int i = 0; i < 6; ++i) {             // 12 aligned float2 loads; halo -> L1
        const float2 xv = *(const float2*)(px + 2 * i);
        const float2 yv = *(const float2*)(py + 2 * i);
        x[2 * i] = xv.x; x[2 * i + 1] = xv.y;
        y[2 * i] = yv.x; y[2 * i + 1] = yv.y;
    }

    // Horizontal blur, 12 taps with per-lane parity-shifted weights.
    // Even lane: W = {G0..G10, 0}; odd lane: W = {0, G0..G10}. The zero tap
    // contributes fmaf(0,v,h)==h exactly -> bit-identical to 11-tap order.
    float h0 = 0.f, h1 = 0.f, h2 = 0.f, h3 = 0.f, h4 = 0.f;
    #pragma unroll
    for (int k = 0; k < 12; ++k) {
        const float w = W[k];
        h0 = fmaf(w, x[k], h0);
        h1 = fmaf(w, y[k], h1);
        const float xx = x[k] * x[k];
        h2 = fmaf(w, xx, h2);
        const float yy = y[k] * y[k];
        h3 = fmaf(w, yy, h3);
        const float xy = x[k] * y[k];
        h4 = fmaf(w, xy, h4);
    }

    // Row r contributes weight G[d] to output row r-d; slot (p-d) mod 11.
    // d==0 ASSIGNS its slot (freed by last phase's emit) -> no init/reset.
    #pragma unroll
    for (int d = 0; d < WIN; ++d) {
        const int s = (PH - d + 2 * WIN) % WIN;   // literal constant after unroll
        const float g = G[d];
        a[0][s] = (d == 0) ? (g * h0) : fmaf(g, h0, a[0][s]);
        a[1][s] = (d == 0) ? (g * h1) : fmaf(g, h1, a[1][s]);
        a[2][s] = (d == 0) ? (g * h2) : fmaf(g, h2, a[2][s]);
        a[3][s] = (d == 0) ? (g * h3) : fmaf(g, h3, a[3][s]);
        a[4][s] = (d == 0) ? (g * h4) : fmaf(g, h4, a[4][s]);
    }

    // Output row o = r-10 completed this phase; its slot is (PH+1)%11.
    if (p >= WIN - 1) {
        const int o = r0 + p - (WIN - 1);
        if (o < OUT_DIM && c < OUT_DIM) {
            constexpr int se = (PH + 1) % WIN;
            const float C1 = 0.0001f, C2 = 0.0009f;
            const float m1 = a[0][se], m2 = a[1][se];
            const float m1sq = m1 * m1, m2sq = m2 * m2, m12 = m1 * m2;
            const float s1  = a[2][se] - m1sq;
            const float s2  = a[3][se] - m2sq;
            const float s12 = a[4][se] - m12;
            const float num = (2.f * m12 + C1) * (2.f * s12 + C2);
            const float den = (m1sq + m2sq + C1) * (s1 + s2 + C2);
            local += num * __builtin_amdgcn_rcpf(den);
        }
    }
}

__global__ __launch_bounds__(256, 4) void ssim_stream(const float* __restrict__ X,
                                                      const float* __restrict__ Y,
                                                      float* __restrict__ planeSums) {
    constexpr float G[WIN] = {0.00102838f, 0.00759875f, 0.03600077f, 0.10936071f,
                              0.21300553f, 0.26601172f, 0.21300553f, 0.10936071f,
                              0.03600077f, 0.00759875f, 0.00102838f};
    const int tid = threadIdx.x;
    const int r0 = blockIdx.x * BH;
    const int c = (blockIdx.y << 8) + tid;    // this lane's single output col
    const int plane = blockIdx.z;
    const size_t pbase = (size_t)plane * IMG * IMG;
    const float* Xp = X + pbase;
    const float* Yp = Y + pbase;
    const int cbase = min(c & ~1, IMG - 12);  // aligned window base; clamp keeps
                                              // loads in-bounds, clamped lanes never emit

    // Per-lane 12-tap weights: even = {G,0}, odd = {0,G}. 12 cndmasks, hoisted.
    float W[12];
    const bool odd = (c & 1) != 0;
    W[0] = odd ? 0.f : G[0];
    #pragma unroll
    for (int k = 1; k < 11; ++k) W[k] = odd ? G[k - 1] : G[k];
    W[11] = odd ? G[10] : 0.f;

    float a[5][WIN];                          // 55 regs once SROA'd
    float local = 0.f;

    for (int base = 0; base < 44; base += WIN) {  // 4 x 11 phases, guard trims to 42
        phase_step<0>(base, r0, c, cbase, Xp, Yp, W, a, local);
        phase_step<1>(base, r0, c, cbase, Xp, Yp, W, a, local);
        phase_step<2>(base, r0, c, cbase, Xp, Yp, W, a, local);
        phase_step<3>(base, r0, c, cbase, Xp, Yp, W, a, local);
        phase_step<4>(base, r0, c, cbase, Xp, Yp, W, a, local);
        phase_step<5>(base, r0, c, cbase, Xp, Yp, W, a, local);
        phase_step<6>(base, r0, c, cbase, Xp, Yp, W, a, local);
        phase_step<7>(base, r0, c, cbase, Xp, Yp, W, a, local);
        phase_step<8>(base, r0, c, cbase, Xp, Yp, W, a, local);
        phase_step<9>(base, r0, c, cbase, Xp, Yp, W, a, local);
        phase_step<10>(base, r0, c, cbase, Xp, Yp, W, a, local);
    }

    // Block reduction -> one atomic per block (32 blocks/plane).
    #pragma unroll
    for (int off = 32; off > 0; off >>= 1)
        local += __shfl_down(local, off, 64);
    __shared__ float red[4];
    if ((tid & 63) == 0) red[tid >> 6] = local;
    __syncthreads();
    if (tid == 0)
        atomicAdd(&planeSums[plane], (red[0] + red[1]) + (red[2] + red[3]));
}

__global__ __launch_bounds__(128) void ssim_finalize(const float* __restrict__ planeSums,
                                                     float* __restrict__ out) {
    const int tid = threadIdx.x;
    float v = 0.f;
    if (tid < NPLANES) {
        const float m = planeSums[tid] * (1.0f / (float)(OUT_DIM * OUT_DIM));
        v = fmaxf(m, 0.f);   // nonnegative_ssim relu
    }
    #pragma unroll
    for (int off = 32; off > 0; off >>= 1)
        v += __shfl_down(v, off, 64);
    __shared__ float red[2];
    if ((tid & 63) == 0) red[tid >> 6] = v;
    __syncthreads();
    if (tid == 0) out[0] = 1.0f - (red[0] + red[1]) * (1.0f / (float)NPLANES);
}

extern "C" void kernel_launch(void* const* d_in, const int* in_sizes, int n_in,
                              void* d_out, int out_size, void* d_ws, size_t ws_size,
                              hipStream_t stream) {
    const float* X = (const float*)d_in[0];   // predictions
    const float* Y = (const float*)d_in[1];   // labels
    float* out = (float*)d_out;
    float* ws  = (float*)d_ws;                // 96 per-plane sums

    hipMemsetAsync(ws, 0, NPLANES * sizeof(float), stream);

    dim3 grid((OUT_DIM + BH - 1) / BH, 2, NPLANES);   // 16 x 2 x 96 = 3072 blocks
    ssim_stream<<<grid, 256, 0, stream>>>(X, Y, ws);
    ssim_finalize<<<1, 128, 0, stream>>>(ws, out);
}